// Round 1
// baseline (1816.594 us; speedup 1.0000x reference)
//
#include <hip/hip_runtime.h>

#define D 64
#define TILE 64
#define TPAD 68  // tile row stride (floats): 16B-aligned, breaks 64-stride conflicts

// ---------------- CSR build ----------------

__global__ void hist_kernel(const int* __restrict__ dst, int E, int* __restrict__ counts) {
    int i = blockIdx.x * blockDim.x + threadIdx.x;
    if (i < E) atomicAdd(&counts[dst[i]], 1);
}

__global__ void scan_kernel(const int* __restrict__ counts, int* __restrict__ offs,
                            int* __restrict__ cursor, int n) {
    __shared__ int sums[1024];
    int t = threadIdx.x;
    int chunk = (n + 1023) / 1024;
    int s = t * chunk, e = s + chunk;
    if (s > n) s = n;
    if (e > n) e = n;
    int local = 0;
    for (int i = s; i < e; i++) local += counts[i];
    sums[t] = local;
    __syncthreads();
    for (int off = 1; off < 1024; off <<= 1) {
        int v = sums[t];
        int u = (t >= off) ? sums[t - off] : 0;
        __syncthreads();
        sums[t] = v + u;
        __syncthreads();
    }
    int base = (t == 0) ? 0 : sums[t - 1];
    for (int i = s; i < e; i++) {
        offs[i] = base;
        cursor[i] = base;
        base += counts[i];
    }
    if (t == 1023) offs[n] = sums[1023];
}

__global__ void fill_kernel(const int* __restrict__ src, const int* __restrict__ dst, int E,
                            int* __restrict__ cursor, int* __restrict__ colA) {
    int i = blockIdx.x * blockDim.x + threadIdx.x;
    if (i < E) {
        int d = dst[i];
        int p = atomicAdd(&cursor[d], 1);
        colA[p] = src[i];
    }
}

// ---------------- fused GIN block (+optional final linear) ----------------
// One block = 256 threads = 4 waves handles TILE=64 nodes.
// Phase A: wave wv aggregates nodes [base+wv*16, +16), lane = feature dim.
// Phase B: thread (wv, lane) computes out-dim `lane` for 16 nodes of group wv.

__global__ __launch_bounds__(256) void gin_kernel(
    const float* __restrict__ xin,
    const int* __restrict__ offs, const int* __restrict__ colA,
    const float* __restrict__ w1, const float* __restrict__ b1,
    const float* __restrict__ w2, const float* __restrict__ b2,
    const float* __restrict__ wf, const float* __restrict__ bf,  // nullable => no final mm
    float* __restrict__ xout, int n) {
    __shared__ float wsm[D * D];
    __shared__ float ta[TILE * TPAD];
    __shared__ float tb[TILE * TPAD];
    const int t = threadIdx.x;
    const int lane = t & 63;
    const int wv = t >> 6;
    const int base = blockIdx.x * TILE;

    // stage w1
    for (int i = t; i < D * D; i += 256) wsm[i] = w1[i];

    // Phase A: aggregation (self + neighbor sum), one node per wave-iteration
    for (int r = 0; r < 16; r++) {
        int nn = base + wv * 16 + r;
        float acc = 0.f;
        if (nn < n) {
            acc = xin[nn * D + lane];
            int s0 = offs[nn], e0 = offs[nn + 1];
            for (int k = s0; k < e0; k++) {
                acc += xin[colA[k] * D + lane];
            }
        }
        ta[(wv * 16 + r) * TPAD + lane] = acc;
    }
    __syncthreads();

    // mm1: relu(ta @ w1 + b1) -> tb
    {
        float bias = b1[lane];
        float acc[16];
#pragma unroll
        for (int i2 = 0; i2 < 16; i2++) acc[i2] = bias;
        for (int d = 0; d < D; d += 4) {
            float w0 = wsm[(d + 0) * D + lane];
            float w1v = wsm[(d + 1) * D + lane];
            float w2v = wsm[(d + 2) * D + lane];
            float w3v = wsm[(d + 3) * D + lane];
#pragma unroll
            for (int i2 = 0; i2 < 16; i2++) {
                const float4 h = *(const float4*)&ta[(wv * 16 + i2) * TPAD + d];
                acc[i2] += h.x * w0 + h.y * w1v + h.z * w2v + h.w * w3v;
            }
        }
#pragma unroll
        for (int i2 = 0; i2 < 16; i2++) tb[(wv * 16 + i2) * TPAD + lane] = fmaxf(acc[i2], 0.f);
    }
    __syncthreads();
    for (int i = t; i < D * D; i += 256) wsm[i] = w2[i];
    __syncthreads();

    // mm2: relu(tb @ w2 + b2) -> ta (if final mm follows) or global
    {
        float bias = b2[lane];
        float acc[16];
#pragma unroll
        for (int i2 = 0; i2 < 16; i2++) acc[i2] = bias;
        for (int d = 0; d < D; d += 4) {
            float w0 = wsm[(d + 0) * D + lane];
            float w1v = wsm[(d + 1) * D + lane];
            float w2v = wsm[(d + 2) * D + lane];
            float w3v = wsm[(d + 3) * D + lane];
#pragma unroll
            for (int i2 = 0; i2 < 16; i2++) {
                const float4 h = *(const float4*)&tb[(wv * 16 + i2) * TPAD + d];
                acc[i2] += h.x * w0 + h.y * w1v + h.z * w2v + h.w * w3v;
            }
        }
        if (wf) {
#pragma unroll
            for (int i2 = 0; i2 < 16; i2++) ta[(wv * 16 + i2) * TPAD + lane] = fmaxf(acc[i2], 0.f);
        } else {
#pragma unroll
            for (int i2 = 0; i2 < 16; i2++) {
                int nn = base + wv * 16 + i2;
                if (nn < n) xout[nn * D + lane] = fmaxf(acc[i2], 0.f);
            }
        }
    }

    if (wf) {
        __syncthreads();
        for (int i = t; i < D * D; i += 256) wsm[i] = wf[i];
        __syncthreads();
        float bias = bf[lane];
        float acc[16];
#pragma unroll
        for (int i2 = 0; i2 < 16; i2++) acc[i2] = bias;
        for (int d = 0; d < D; d += 4) {
            float w0 = wsm[(d + 0) * D + lane];
            float w1v = wsm[(d + 1) * D + lane];
            float w2v = wsm[(d + 2) * D + lane];
            float w3v = wsm[(d + 3) * D + lane];
#pragma unroll
            for (int i2 = 0; i2 < 16; i2++) {
                const float4 h = *(const float4*)&ta[(wv * 16 + i2) * TPAD + d];
                acc[i2] += h.x * w0 + h.y * w1v + h.z * w2v + h.w * w3v;
            }
        }
#pragma unroll
        for (int i2 = 0; i2 < 16; i2++) {
            int nn = base + wv * 16 + i2;
            if (nn < n) xout[nn * D + lane] = acc[i2];  // no relu on final head
        }
    }
}

// ---------------- launch ----------------

extern "C" void kernel_launch(void* const* d_in, const int* in_sizes, int n_in,
                              void* d_out, int out_size, void* d_ws, size_t ws_size,
                              hipStream_t stream) {
    const float* x = (const float*)d_in[0];
    const int* eidx = (const int*)d_in[1];
    const int N = in_sizes[0] / D;
    const int E = in_sizes[1] / 2;

    const float* w1b[3] = {(const float*)d_in[2], (const float*)d_in[6], (const float*)d_in[10]};
    const float* b1b[3] = {(const float*)d_in[3], (const float*)d_in[7], (const float*)d_in[11]};
    const float* w2b[3] = {(const float*)d_in[4], (const float*)d_in[8], (const float*)d_in[12]};
    const float* b2b[3] = {(const float*)d_in[5], (const float*)d_in[9], (const float*)d_in[13]};
    const float* wf = (const float*)d_in[14];
    const float* bf = (const float*)d_in[15];
    float* out = (float*)d_out;

    // workspace layout (all 4-byte types)
    int* offs = (int*)d_ws;            // N+1
    int* cursor = offs + (N + 1);      // N
    int* counts = cursor + N;          // N
    int* colA = counts + N;            // E
    float* xbuf = (float*)(colA + E);  // N*D

    const int* srcP = eidx;
    const int* dstP = eidx + E;

    hipMemsetAsync(counts, 0, (size_t)N * 4, stream);
    hist_kernel<<<(E + 255) / 256, 256, 0, stream>>>(dstP, E, counts);
    scan_kernel<<<1, 1024, 0, stream>>>(counts, offs, cursor, N);
    fill_kernel<<<(E + 255) / 256, 256, 0, stream>>>(srcP, dstP, E, cursor, colA);

    const int grid = (N + TILE - 1) / TILE;
    // block 0: x -> out ; block 1: out -> xbuf ; block 2 (+final head): xbuf -> out
    gin_kernel<<<grid, 256, 0, stream>>>(x, offs, colA, w1b[0], b1b[0], w2b[0], b2b[0],
                                         nullptr, nullptr, out, N);
    gin_kernel<<<grid, 256, 0, stream>>>(out, offs, colA, w1b[1], b1b[1], w2b[1], b2b[1],
                                         nullptr, nullptr, xbuf, N);
    gin_kernel<<<grid, 256, 0, stream>>>(xbuf, offs, colA, w1b[2], b1b[2], w2b[2], b2b[2],
                                         wf, bf, out, N);
}

// Round 2
// 670.340 us; speedup vs baseline: 2.7100x; 2.7100x over previous
//
#include <hip/hip_runtime.h>

#define D 64
#define TILE 64
#define TPAD 68  // LDS row stride (floats): multiple of 4 (16B-aligned float4), breaks 64-stride

__device__ __forceinline__ void f4add(float4& a, const float4& b) {
    a.x += b.x; a.y += b.y; a.z += b.z; a.w += b.w;
}

// ---------------- CSR build (scan-free) ----------------

__global__ void hist_kernel(const int* __restrict__ dst, int E, int* __restrict__ counts) {
    int i = blockIdx.x * blockDim.x + threadIdx.x;
    if (i < E) atomicAdd(&counts[dst[i]], 1);
}

// start[i] = atomicAdd(total, counts[i]); segments in arbitrary order — CSR doesn't care.
__global__ void alloc_kernel(const int* __restrict__ counts, int* __restrict__ start,
                             int* __restrict__ cursor, int* __restrict__ total, int n) {
    int i = blockIdx.x * blockDim.x + threadIdx.x;
    if (i < n) {
        int c = counts[i];
        int p = atomicAdd(total, c);
        start[i] = p;
        cursor[i] = p;
    }
}

__global__ void fill_kernel(const int* __restrict__ src, const int* __restrict__ dst, int E,
                            int* __restrict__ cursor, int* __restrict__ colA) {
    int i = blockIdx.x * blockDim.x + threadIdx.x;
    if (i < E) {
        int p = atomicAdd(&cursor[dst[i]], 1);
        colA[p] = src[i];
    }
}

// ---------------- fused GIN block (+optional final linear) ----------------
// 256 threads = 4 waves handle TILE=64 nodes.
// Phase A: 16 groups of 16 threads; group g aggregates rows g*4..g*4+3,
//          lane-within-group = float4 feature quad; neighbor loop unrolled x4
//          with 4 independent accumulators (~64 loads in flight per block).
// MLP:     thread (wv=t>>6, lane=t&63) computes out-dim `lane` for 16 rows,
//          in-place on ta (wave reads all its rows before writing — safe).

__global__ __launch_bounds__(256) void gin_kernel(
    const float* __restrict__ xin,
    const int* __restrict__ start, const int* __restrict__ cnt,
    const int* __restrict__ colA,
    const float* __restrict__ w1, const float* __restrict__ b1,
    const float* __restrict__ w2, const float* __restrict__ b2,
    const float* __restrict__ wf, const float* __restrict__ bf,  // nullable => no final mm
    float* __restrict__ xout, int n) {
    __shared__ float wsm[D * D];
    __shared__ float ta[TILE * TPAD];
    const int t = threadIdx.x;
    const int lane = t & 63;
    const int wv = t >> 6;
    const int base = blockIdx.x * TILE;
    const int g = t >> 4;  // 0..15
    const int l = t & 15;  // float4 quad index

    // stage w1 (consumed after the Phase-A barrier)
    for (int i = t; i < D * D; i += 256) wsm[i] = w1[i];

    // Phase A: aggregation (self + neighbor sum)
    for (int r = 0; r < 4; r++) {
        const int row = g * 4 + r;
        const int nn = base + row;
        float4 a0 = make_float4(0.f, 0.f, 0.f, 0.f);
        float4 a1 = a0, a2 = a0, a3 = a0;
        if (nn < n) {
            a0 = *(const float4*)&xin[nn * D + l * 4];
            int k = start[nn];
            const int e0 = k + cnt[nn];
            for (; k + 4 <= e0; k += 4) {
                const int c0 = colA[k], c1 = colA[k + 1], c2 = colA[k + 2], c3 = colA[k + 3];
                float4 v0 = *(const float4*)&xin[c0 * D + l * 4];
                float4 v1 = *(const float4*)&xin[c1 * D + l * 4];
                float4 v2 = *(const float4*)&xin[c2 * D + l * 4];
                float4 v3 = *(const float4*)&xin[c3 * D + l * 4];
                f4add(a0, v0); f4add(a1, v1); f4add(a2, v2); f4add(a3, v3);
            }
            for (; k < e0; k++) {
                float4 v = *(const float4*)&xin[colA[k] * D + l * 4];
                f4add(a0, v);
            }
        }
        f4add(a0, a1); f4add(a2, a3); f4add(a0, a2);
        *(float4*)&ta[row * TPAD + l * 4] = a0;
    }
    __syncthreads();

    // mm1: relu(ta @ w1 + b1) -> ta (in place)
    {
        const float bias = b1[lane];
        float acc[16];
#pragma unroll
        for (int i2 = 0; i2 < 16; i2++) acc[i2] = bias;
        for (int d = 0; d < D; d += 4) {
            const float w0 = wsm[(d + 0) * D + lane];
            const float w1v = wsm[(d + 1) * D + lane];
            const float w2v = wsm[(d + 2) * D + lane];
            const float w3v = wsm[(d + 3) * D + lane];
#pragma unroll
            for (int i2 = 0; i2 < 16; i2++) {
                const float4 h = *(const float4*)&ta[(wv * 16 + i2) * TPAD + d];
                acc[i2] += h.x * w0 + h.y * w1v + h.z * w2v + h.w * w3v;
            }
        }
#pragma unroll
        for (int i2 = 0; i2 < 16; i2++) ta[(wv * 16 + i2) * TPAD + lane] = fmaxf(acc[i2], 0.f);
    }
    __syncthreads();
    for (int i = t; i < D * D; i += 256) wsm[i] = w2[i];
    __syncthreads();

    // mm2: relu(ta @ w2 + b2) -> ta (if final mm follows) or global
    {
        const float bias = b2[lane];
        float acc[16];
#pragma unroll
        for (int i2 = 0; i2 < 16; i2++) acc[i2] = bias;
        for (int d = 0; d < D; d += 4) {
            const float w0 = wsm[(d + 0) * D + lane];
            const float w1v = wsm[(d + 1) * D + lane];
            const float w2v = wsm[(d + 2) * D + lane];
            const float w3v = wsm[(d + 3) * D + lane];
#pragma unroll
            for (int i2 = 0; i2 < 16; i2++) {
                const float4 h = *(const float4*)&ta[(wv * 16 + i2) * TPAD + d];
                acc[i2] += h.x * w0 + h.y * w1v + h.z * w2v + h.w * w3v;
            }
        }
        if (wf) {
#pragma unroll
            for (int i2 = 0; i2 < 16; i2++) ta[(wv * 16 + i2) * TPAD + lane] = fmaxf(acc[i2], 0.f);
        } else {
#pragma unroll
            for (int i2 = 0; i2 < 16; i2++) {
                const int nn = base + wv * 16 + i2;
                if (nn < n) xout[nn * D + lane] = fmaxf(acc[i2], 0.f);
            }
        }
    }

    if (wf) {
        __syncthreads();
        for (int i = t; i < D * D; i += 256) wsm[i] = wf[i];
        __syncthreads();
        const float bias = bf[lane];
        float acc[16];
#pragma unroll
        for (int i2 = 0; i2 < 16; i2++) acc[i2] = bias;
        for (int d = 0; d < D; d += 4) {
            const float w0 = wsm[(d + 0) * D + lane];
            const float w1v = wsm[(d + 1) * D + lane];
            const float w2v = wsm[(d + 2) * D + lane];
            const float w3v = wsm[(d + 3) * D + lane];
#pragma unroll
            for (int i2 = 0; i2 < 16; i2++) {
                const float4 h = *(const float4*)&ta[(wv * 16 + i2) * TPAD + d];
                acc[i2] += h.x * w0 + h.y * w1v + h.z * w2v + h.w * w3v;
            }
        }
#pragma unroll
        for (int i2 = 0; i2 < 16; i2++) {
            const int nn = base + wv * 16 + i2;
            if (nn < n) xout[nn * D + lane] = acc[i2];  // no relu on final head
        }
    }
}

// ---------------- launch ----------------

extern "C" void kernel_launch(void* const* d_in, const int* in_sizes, int n_in,
                              void* d_out, int out_size, void* d_ws, size_t ws_size,
                              hipStream_t stream) {
    const float* x = (const float*)d_in[0];
    const int* eidx = (const int*)d_in[1];
    const int N = in_sizes[0] / D;
    const int E = in_sizes[1] / 2;

    const float* w1b[3] = {(const float*)d_in[2], (const float*)d_in[6], (const float*)d_in[10]};
    const float* b1b[3] = {(const float*)d_in[3], (const float*)d_in[7], (const float*)d_in[11]};
    const float* w2b[3] = {(const float*)d_in[4], (const float*)d_in[8], (const float*)d_in[12]};
    const float* b2b[3] = {(const float*)d_in[5], (const float*)d_in[9], (const float*)d_in[13]};
    const float* wf = (const float*)d_in[14];
    const float* bf = (const float*)d_in[15];
    float* out = (float*)d_out;

    // workspace layout (all 4-byte types)
    int* start = (int*)d_ws;            // N
    int* cursor = start + N;            // N
    int* counts = cursor + N;           // N + 1  (counts[N] = global total cursor)
    int* colA = counts + (N + 1);       // E
    float* xbuf = (float*)(colA + E);   // N*D

    const int* srcP = eidx;
    const int* dstP = eidx + E;

    hipMemsetAsync(counts, 0, (size_t)(N + 1) * 4, stream);
    hist_kernel<<<(E + 255) / 256, 256, 0, stream>>>(dstP, E, counts);
    alloc_kernel<<<(N + 255) / 256, 256, 0, stream>>>(counts, start, cursor, counts + N, N);
    fill_kernel<<<(E + 255) / 256, 256, 0, stream>>>(srcP, dstP, E, cursor, colA);

    const int grid = (N + TILE - 1) / TILE;
    // block 0: x -> out ; block 1: out -> xbuf ; block 2 (+final head): xbuf -> out
    gin_kernel<<<grid, 256, 0, stream>>>(x, start, counts, colA, w1b[0], b1b[0], w2b[0], b2b[0],
                                         nullptr, nullptr, out, N);
    gin_kernel<<<grid, 256, 0, stream>>>(out, start, counts, colA, w1b[1], b1b[1], w2b[1], b2b[1],
                                         nullptr, nullptr, xbuf, N);
    gin_kernel<<<grid, 256, 0, stream>>>(xbuf, start, counts, colA, w1b[2], b1b[2], w2b[2], b2b[2],
                                         wf, bf, out, N);
}